// Round 1
// baseline (513.541 us; speedup 1.0000x reference)
//
#include <hip/hip_runtime.h>

#define H 128
#define NTYPES 28
// counts: 1 byte per (cycle,type), padded to 32 bytes (8 dwords) per cycle
#define CNT_DW_PER_CYCLE 8

__global__ void zero_u4_kernel(uint4* __restrict__ p, int n4) {
    int i = blockIdx.x * blockDim.x + threadIdx.x;
    if (i < n4) p[i] = make_uint4(0u, 0u, 0u, 0u);
}

// One thread per incidence: bump packed byte counter cnt[cycle][type].
__global__ void count_kernel(const int* __restrict__ a2c,
                             const int* __restrict__ x,
                             unsigned* __restrict__ cnt,
                             int n_inc) {
    int e = blockIdx.x * blockDim.x + threadIdx.x;
    if (e >= n_inc) return;
    int atom = a2c[e];            // row 0
    int cyc  = a2c[n_inc + e];    // row 1
    int t    = x[atom];           // 0..27
    atomicAdd(&cnt[(cyc << 3) + (t >> 2)], 1u << (8 * (t & 3)));
}

// One wave per cycle: out[c][:] = sum_t cnt[c][t] * emb[t][:]
__global__ __launch_bounds__(256) void expand_kernel(
        const unsigned* __restrict__ cnt,
        const float* __restrict__ emb,
        float* __restrict__ out,
        int num_cycles) {
    __shared__ __align__(16) float lds[NTYPES * H];
    for (int i = threadIdx.x; i < NTYPES * H; i += blockDim.x) lds[i] = emb[i];
    __syncthreads();

    int wave = threadIdx.x >> 6;          // 0..3
    int lane = threadIdx.x & 63;
    int c = blockIdx.x * 4 + wave;
    if (c >= num_cycles) return;

    const uint4* cp = (const uint4*)(cnt + (size_t)c * CNT_DW_PER_CYCLE);
    uint4 d0 = cp[0];
    uint4 d1 = cp[1];
    // Counts are wave-uniform; pin them to SGPRs so the per-type zero-skip
    // branch is a scalar s_cbranch (no exec-mask divergence, skips LDS reads).
    unsigned s[8];
    s[0] = (unsigned)__builtin_amdgcn_readfirstlane((int)d0.x);
    s[1] = (unsigned)__builtin_amdgcn_readfirstlane((int)d0.y);
    s[2] = (unsigned)__builtin_amdgcn_readfirstlane((int)d0.z);
    s[3] = (unsigned)__builtin_amdgcn_readfirstlane((int)d0.w);
    s[4] = (unsigned)__builtin_amdgcn_readfirstlane((int)d1.x);
    s[5] = (unsigned)__builtin_amdgcn_readfirstlane((int)d1.y);
    s[6] = (unsigned)__builtin_amdgcn_readfirstlane((int)d1.z);
    s[7] = (unsigned)__builtin_amdgcn_readfirstlane((int)d1.w);

    float2 acc = {0.f, 0.f};
    const float2* l2 = (const float2*)lds;
#pragma unroll
    for (int t = 0; t < NTYPES; ++t) {
        unsigned cv = (s[t >> 2] >> (8 * (t & 3))) & 0xFFu;
        if (cv) {
            float f = (float)cv;
            float2 w = l2[t * 64 + lane];
            acc.x += f * w.x;
            acc.y += f * w.y;
        }
    }
    float2* op = (float2*)(out + (size_t)c * H);
    op[lane] = acc;   // 64 lanes x 8B = contiguous 512B store
}

// ---- fallback path (ws too small): direct atomic scatter of rows ----
__global__ void scatter_direct_kernel(const int* __restrict__ a2c,
                                      const int* __restrict__ x,
                                      const float* __restrict__ emb,
                                      float* __restrict__ out,
                                      int n_inc) {
    int gid = blockIdx.x * blockDim.x + threadIdx.x;
    int e  = gid >> 5;
    int ch = gid & 31;            // 32 chunks of float4 = 128 dims
    if (e >= n_inc) return;
    int atom = a2c[e];
    int cyc  = a2c[n_inc + e];
    int t    = x[atom];
    const float4 w = ((const float4*)(emb + t * H))[ch];
    float* o = out + (size_t)cyc * H + ch * 4;
    atomicAdd(o + 0, w.x);
    atomicAdd(o + 1, w.y);
    atomicAdd(o + 2, w.z);
    atomicAdd(o + 3, w.w);
}

extern "C" void kernel_launch(void* const* d_in, const int* in_sizes, int n_in,
                              void* d_out, int out_size, void* d_ws, size_t ws_size,
                              hipStream_t stream) {
    const int*   x    = (const int*)d_in[0];
    const int*   a2c  = (const int*)d_in[1];
    const float* emb  = (const float*)d_in[2];
    float*       out  = (float*)d_out;

    const int n_inc      = in_sizes[1] / 2;
    const int num_cycles = out_size / H;

    const size_t cnt_bytes = (size_t)num_cycles * CNT_DW_PER_CYCLE * 4;

    if (ws_size >= cnt_bytes) {
        unsigned* cnt = (unsigned*)d_ws;
        // 1) zero counts
        int n4 = (int)(cnt_bytes / 16);
        zero_u4_kernel<<<(n4 + 255) / 256, 256, 0, stream>>>((uint4*)d_ws, n4);
        // 2) count per (cycle,type)
        count_kernel<<<(n_inc + 255) / 256, 256, 0, stream>>>(a2c, x, cnt, n_inc);
        // 3) expand: one wave per cycle
        int blocks = (num_cycles + 3) / 4;
        expand_kernel<<<blocks, 256, 0, stream>>>(cnt, emb, out, num_cycles);
    } else {
        // fallback: zero output then direct atomic scatter
        int n4 = out_size / 4;
        zero_u4_kernel<<<(n4 + 255) / 256, 256, 0, stream>>>((uint4*)d_out, n4);
        long long total = (long long)n_inc * 32;
        int blocks = (int)((total + 255) / 256);
        scatter_direct_kernel<<<blocks, 256, 0, stream>>>(a2c, x, emb, out, n_inc);
    }
}

// Round 2
// 362.705 us; speedup vs baseline: 1.4159x; 1.4159x over previous
//
#include <hip/hip_runtime.h>
#include <string.h>

#define H 128
#define NTYPES 28
#define CNT_BYTES_PER_CYCLE 32   // 28 byte counters + 4 pad, dword-packed

// ---- count: one incidence -> +1 on byte counter cnt[cycle][type] ----
// 4 incidences per thread, int4 loads on both index rows.
__global__ void count_kernel(const int* __restrict__ a2c,
                             const int* __restrict__ x,
                             unsigned* __restrict__ cnt,
                             int n_inc) {
    int i = (blockIdx.x * blockDim.x + threadIdx.x) * 4;
    if (i + 3 < n_inc) {
        int4 at = *(const int4*)(a2c + i);
        int4 cy = *(const int4*)(a2c + n_inc + i);
        int t0 = x[at.x], t1 = x[at.y], t2 = x[at.z], t3 = x[at.w];
        atomicAdd(&cnt[cy.x * 8 + (t0 >> 2)], 1u << (8 * (t0 & 3)));
        atomicAdd(&cnt[cy.y * 8 + (t1 >> 2)], 1u << (8 * (t1 & 3)));
        atomicAdd(&cnt[cy.z * 8 + (t2 >> 2)], 1u << (8 * (t2 & 3)));
        atomicAdd(&cnt[cy.w * 8 + (t3 >> 2)], 1u << (8 * (t3 & 3)));
    } else {
        for (int e = i; e < n_inc; ++e) {
            int atom = a2c[e];
            int cycv = a2c[n_inc + e];
            int t = x[atom];
            atomicAdd(&cnt[cycv * 8 + (t >> 2)], 1u << (8 * (t & 3)));
        }
    }
}

// ---- expand: one wave per cycle (grid-stride): out[c] = sum_t cnt[c][t]*emb[t] ----
// Lane i (i<28 effective) supplies count byte i; __ballot builds the nonzero-type
// mask in one instr; s_ff1 loop + readlane pulls each count to SGPR. Avg ~4
// nonzero types/cycle -> ~4 ds_read_b64 + FMAs per cycle.
__global__ __launch_bounds__(256) void expand_kernel(
        const unsigned char* __restrict__ cnt,
        const float* __restrict__ emb,
        float* __restrict__ out,
        int num_cycles) {
    __shared__ __align__(16) float lds[NTYPES * H];
    for (int i = threadIdx.x; i < NTYPES * H; i += blockDim.x) lds[i] = emb[i];
    __syncthreads();
    const float2* l2 = (const float2*)lds;

    int lane = threadIdx.x & 63;
    int w    = blockIdx.x * (blockDim.x >> 6) + (threadIdx.x >> 6);
    int nw   = gridDim.x * (blockDim.x >> 6);

    for (int c = w; c < num_cycles; c += nw) {
        // 32B counter line; lanes 32..63 re-read bytes 0..31 (same cache line).
        unsigned b = cnt[(size_t)c * CNT_BYTES_PER_CYCLE + (lane & 31)];
        unsigned long long m = __ballot(b != 0) & 0x0FFFFFFFull;
        float2 acc = {0.f, 0.f};
        while (m) {
            int t = __builtin_ctzll(m);   // s_ff1 on uniform mask
            m &= m - 1;
            float f = (float)__builtin_amdgcn_readlane((int)b, t);
            float2 wv = l2[t * 64 + lane];
            acc.x += f * wv.x;
            acc.y += f * wv.y;
        }
        // streaming 8B/lane nontemporal store (512B/wave contiguous)
        unsigned long long bits;
        memcpy(&bits, &acc, 8);
        __builtin_nontemporal_store(
            bits, (unsigned long long*)(out + (size_t)c * H) + lane);
    }
}

// ---- fallback (ws too small): direct atomic scatter ----
__global__ void scatter_direct_kernel(const int* __restrict__ a2c,
                                      const int* __restrict__ x,
                                      const float* __restrict__ emb,
                                      float* __restrict__ out,
                                      int n_inc) {
    int gid = blockIdx.x * blockDim.x + threadIdx.x;
    int e  = gid >> 5;
    int ch = gid & 31;
    if (e >= n_inc) return;
    int atom = a2c[e];
    int cyc  = a2c[n_inc + e];
    int t    = x[atom];
    const float4 w = ((const float4*)(emb + t * H))[ch];
    float* o = out + (size_t)cyc * H + ch * 4;
    atomicAdd(o + 0, w.x);
    atomicAdd(o + 1, w.y);
    atomicAdd(o + 2, w.z);
    atomicAdd(o + 3, w.w);
}

__global__ void zero_u4_kernel(uint4* __restrict__ p, int n4) {
    int i = blockIdx.x * blockDim.x + threadIdx.x;
    if (i < n4) p[i] = make_uint4(0u, 0u, 0u, 0u);
}

extern "C" void kernel_launch(void* const* d_in, const int* in_sizes, int n_in,
                              void* d_out, int out_size, void* d_ws, size_t ws_size,
                              hipStream_t stream) {
    const int*   x    = (const int*)d_in[0];
    const int*   a2c  = (const int*)d_in[1];
    const float* emb  = (const float*)d_in[2];
    float*       out  = (float*)d_out;

    const int n_inc      = in_sizes[1] / 2;
    const int num_cycles = out_size / H;
    const size_t cnt_bytes = (size_t)num_cycles * CNT_BYTES_PER_CYCLE;

    if (ws_size >= cnt_bytes) {
        unsigned* cnt = (unsigned*)d_ws;
        hipMemsetAsync(d_ws, 0, cnt_bytes, stream);
        int nthreads = (n_inc + 3) / 4;
        count_kernel<<<(nthreads + 255) / 256, 256, 0, stream>>>(a2c, x, cnt, n_inc);
        // 2048 blocks x 256 threads = 8192 waves: exactly resident at 32 waves/CU
        expand_kernel<<<2048, 256, 0, stream>>>(
            (const unsigned char*)cnt, emb, out, num_cycles);
    } else {
        int n4 = out_size / 4;
        zero_u4_kernel<<<(n4 + 255) / 256, 256, 0, stream>>>((uint4*)d_out, n4);
        long long total = (long long)n_inc * 32;
        int blocks = (int)((total + 255) / 256);
        scatter_direct_kernel<<<blocks, 256, 0, stream>>>(a2c, x, emb, out, n_inc);
    }
}